// Round 16
// baseline (169.227 us; speedup 1.0000x reference)
//
#include <hip/hip_runtime.h>
#include <hip/hip_bf16.h>

// Problem: B=2,S=2048,D=1024,E=14,F=2048; N=4096 tokens.
// R15 (= R11, proven green, 166.6us) + ONE change: k_gemm2 uses a 128x128
// tile (own body gemm2_body128 + GemmSh2; proven gemm_body template and all
// other kernels byte-identical). Isolation test of the 128^2 geometry far
// from the fuseA/fuseB role-mapping mystery zone.
//
// ws layout (bytes), ws_size ~= 448MB:
//   [0)        ints: cnt[0..14) @0, ntl @ int48, tiles @ int64..160,
//              assign @ int160..4256, wgt(f32) @ int4256..8352
//   [65536)    list: 14 regions x 4096 ints (224KB)
//   [294912)   rwT: transposed router_w (14x1024 f32, 57KB)
//   [393216)   hid bf16 (16.78MB)
//   [17170432) h16 bf16 (8.39MB)
//   [25559040) img1 (29.36MB)  -- swizzled bf16 w1 tile images
//   [54919168) img2 (29.36MB)  -- swizzled bf16 w2 tile images
// total need: 84279296 bytes.
//
// Launch graph (5 dispatches):
//   k_init -> k_fuseA{router || prep(w1)} -> k_sort
//          -> k_fuseB{gemm1 || prep(w2)} -> k_gemm2(128x128)

#define NTOK 4096
#define NEXP 14
#define DDIM 1024
#define FDIM 2048

typedef __attribute__((ext_vector_type(8))) short short8;
typedef __attribute__((ext_vector_type(4))) float floatx4;

__device__ __forceinline__ unsigned bfr(float f) {  // f32 -> bf16 bits, RNE
  unsigned u = __float_as_uint(f);
  return (u + 0x7FFFu + ((u >> 16) & 1u)) >> 16;
}
__device__ __forceinline__ unsigned pk2(float a, float b) {
  return bfr(a) | (bfr(b) << 16);
}

__device__ __forceinline__ void gload16(const void* g, void* l) {
  __builtin_amdgcn_global_load_lds((const __attribute__((address_space(1))) void*)g,
                                   (__attribute__((address_space(3))) void*)l, 16, 0, 0);
}

struct GemmSh {
  char sA[2][16384];  // bf16 [128 rows][64 k], XOR-swizzled via source
  char sB[2][8192];   // bf16 [64 cols][64 k], image bytes == swizzled layout
  int tokL[128];
  float wgtL[128];
};
union FuseSh {
  GemmSh g;
  float t32[4096];
};
struct GemmSh2 {  // 128x128 tile for k_gemm2
  char sA[2][16384];  // bf16 [128 rows][64 k]
  char sB[2][16384];  // 2 n-chunk images x bf16 [64 cols][64 k]
  int tokL[128];
  float wgtL[128];
};

// build transposed router weights rwT[e][d]
__global__ void k_init(const float* __restrict__ rw, float* __restrict__ rwT) {
  int i = blockIdx.x * 256 + threadIdx.x;
  if (i < DDIM * NEXP) rwT[(i % NEXP) * DDIM + i / NEXP] = rw[i];
}

// ---- router body: one wave per token, no LDS, no atomics ----
__device__ __forceinline__ void router_body(
    int bid, const float* __restrict__ x, const float* __restrict__ rwT,
    int* __restrict__ assign, float* __restrict__ wgt,
    unsigned short* __restrict__ h16) {
  int wid = threadIdx.x >> 6, lane = threadIdx.x & 63;
  int n = bid * 4 + wid;
  const float* xr = x + (size_t)n * DDIM;
  unsigned short* hr = h16 + (size_t)n * DDIM;
  double acc[NEXP];
#pragma unroll
  for (int e = 0; e < NEXP; e++) acc[e] = 0.0;
#pragma unroll
  for (int i = 0; i < 4; i++) {
    int d0 = i * 256 + lane * 4;
    float4 xv = *(const float4*)(xr + d0);
    uint2 hb;
    hb.x = pk2(xv.x, xv.y);
    hb.y = pk2(xv.z, xv.w);
    *(uint2*)(hr + d0) = hb;
    double x0 = xv.x, x1 = xv.y, x2 = xv.z, x3 = xv.w;
#pragma unroll
    for (int e = 0; e < NEXP; e++) {
      float4 rv = *(const float4*)(rwT + e * DDIM + d0);
      acc[e] += x0 * (double)rv.x + x1 * (double)rv.y + x2 * (double)rv.z + x3 * (double)rv.w;
    }
  }
#pragma unroll
  for (int e = 0; e < NEXP; e++)
    for (int m = 32; m > 0; m >>= 1) acc[e] += __shfl_xor(acc[e], m, 64);
  int best = 0;
  double bv = acc[0];
#pragma unroll
  for (int e = 1; e < NEXP; e++)
    if (acc[e] > bv) { bv = acc[e]; best = e; }
  float s = 0.f;
#pragma unroll
  for (int e = 0; e < NEXP; e++) s += expf((float)(acc[e] - bv));
  if (lane == 0) {
    wgt[n] = 1.0f / s;
    assign[n] = best;
  }
}

// ---- weight-image prep body: 4 k-tiles per block (z-loop) ----
// Emits exact byte image of the GEMM's swizzled LDS B-tile:
//   chunk ci = col*8 + (k8 ^ (col&7)); bytes = bf16 W[k8*8+j][col], j=0..7.
// LDS f32 transpose tile dword-swizzled: dw = k*64 + (n ^ (k&31)).
__device__ __forceinline__ void prep_body(float* __restrict__ t32,
                                          const float* __restrict__ W,
                                          unsigned short* __restrict__ img,
                                          int K, int N, int b) {
  int KB = K >> 6, NB = N >> 6, K4 = KB >> 2;
  int kb4 = b % K4;
  int nb_ = b / K4;
  int nblk = nb_ % NB, e = nb_ / NB;
  int t = threadIdx.x;
  int k = t >> 4, n4 = (t & 15) * 4;
  for (int z = 0; z < 4; z++) {
    int kblk = kb4 * 4 + z;
    const float* src = W + (size_t)e * K * N + (size_t)(kblk * 64) * N + nblk * 64;
#pragma unroll
    for (int j = 0; j < 4; j++) {
      int kk = k + j * 16;
      float4 v = *(const float4*)(src + (size_t)kk * N + n4);
      int sw = kk & 31;
      t32[kk * 64 + ((n4 + 0) ^ sw)] = v.x;
      t32[kk * 64 + ((n4 + 1) ^ sw)] = v.y;
      t32[kk * 64 + ((n4 + 2) ^ sw)] = v.z;
      t32[kk * 64 + ((n4 + 3) ^ sw)] = v.w;
    }
    __syncthreads();
    unsigned short* dst = img + (size_t)((e * NB + nblk) * KB + kblk) * 4096;
#pragma unroll
    for (int c = 0; c < 2; c++) {
      int ci = t + c * 256;
      int col = ci >> 3, q = ci & 7, k8 = q ^ (col & 7);
      float f[8];
#pragma unroll
      for (int j = 0; j < 8; j++) {
        int kk = k8 * 8 + j;
        f[j] = t32[kk * 64 + (col ^ (kk & 31))];
      }
      uint4 o;
      o.x = pk2(f[0], f[1]);
      o.y = pk2(f[2], f[3]);
      o.z = pk2(f[4], f[5]);
      o.w = pk2(f[6], f[7]);
      *(uint4*)(dst + ci * 8) = o;
    }
    __syncthreads();
  }
}

// ---- fused A: router (1024 blocks) || prep(w1) (1792 blocks) ----
__global__ __launch_bounds__(256) void k_fuseA(
    const float* __restrict__ x, const float* __restrict__ rwT,
    int* __restrict__ assign, float* __restrict__ wgt,
    unsigned short* __restrict__ h16,
    const float* __restrict__ w1, unsigned short* __restrict__ img1) {
  __shared__ float t32[4096];
  int bid = blockIdx.x;
  if (bid < NTOK / 4) {
    router_body(bid, x, rwT, assign, wgt, h16);
  } else {
    prep_body(t32, w1, img1, DDIM, FDIM, bid - NTOK / 4);
  }
}

// single block, 1024 threads: ballot-based stable counting sort, no atomics.
__global__ __launch_bounds__(1024) void k_sort(
    const int* __restrict__ assign, int* __restrict__ cnt,
    int* __restrict__ list, int* __restrict__ tiles, int* __restrict__ ntl) {
  __shared__ int clds[64][NEXP];
  __shared__ int tot[16];
  __shared__ int tstart[NEXP + 1];
  int tid = threadIdx.x;
  int wv = tid >> 6, lane = tid & 63;
  unsigned long long below = (1ull << lane) - 1ull;
  int e4[4], r4[4];
#pragma unroll
  for (int t = 0; t < 4; t++) {
    int n = wv * 256 + t * 64 + lane;
    int e = assign[n];
    int rank = 0, gcnt = 0;
#pragma unroll
    for (int xx = 0; xx < NEXP; xx++) {
      unsigned long long m = __ballot(e == xx);
      if (e == xx) rank = __popcll(m & below);
      if (lane == xx) gcnt = __popcll(m);
    }
    e4[t] = e;
    r4[t] = rank;
    if (lane < NEXP) clds[wv * 4 + t][lane] = gcnt;
  }
  __syncthreads();
  if (wv < NEXP) {
    int v = clds[lane][wv];
    int s = v;
    for (int m = 1; m < 64; m <<= 1) {
      int t = __shfl_up(s, m, 64);
      if (lane >= m) s += t;
    }
    clds[lane][wv] = s - v;
    if (lane == 63) {
      cnt[wv] = s;
      tot[wv] = s;
    }
  }
  __syncthreads();
#pragma unroll
  for (int t = 0; t < 4; t++) {
    int n = wv * 256 + t * 64 + lane;
    int e = e4[t];
    int pos = clds[wv * 4 + t][e] + r4[t];
    list[e * NTOK + pos] = n;
  }
  if (wv == 15) {
    int c = (lane < NEXP) ? tot[lane] : 0;
    int nt = (c + 127) >> 7;
    int st = nt;
    for (int m = 1; m < 64; m <<= 1) {
      int t = __shfl_up(st, m, 64);
      if (lane >= m) st += t;
    }
    if (lane < NEXP) tstart[lane] = st - nt;
    if (lane == NEXP - 1) {
      tstart[NEXP] = st;
      *ntl = st;
    }
    int totT = __shfl(st, NEXP - 1, 64);
    if (lane < totT) {
      int e = 0;
      while (tstart[e + 1] <= lane) e++;
      tiles[2 * lane] = e;
      tiles[2 * lane + 1] = (lane - tstart[e]) * 128;
    }
  }
}

// ---- image-GEMM body: tile 128x64, BK=64, 4 waves (2x2, each 64x32) ----
// BOTH operands via global_load_lds; double-buffered LDS, 2 raw barriers/iter,
// counted s_waitcnt vmcnt(6) (T4 -- never drains in the loop).
template <int LAYER>
__device__ __forceinline__ void gemm_body(
    GemmSh* sh, int tI, int n0,
    const unsigned short* __restrict__ Xb, const unsigned short* __restrict__ img,
    const float* __restrict__ Bias, const float* __restrict__ wgt,
    unsigned short* __restrict__ outB, float* __restrict__ outF,
    const int* __restrict__ wsI, const int* __restrict__ list) {
  constexpr int K = (LAYER == 1) ? DDIM : FDIM;
  constexpr int N = (LAYER == 1) ? FDIM : DDIM;
  constexpr int NIT = K / 64;
  constexpr int KB = K / 64, NB = N / 64;

  const int* cnt = wsI;
  const int* ntl = wsI + 48;
  const int* tiles = wsI + 64;

  if (tI >= *ntl) return;
  int e = tiles[2 * tI], m0 = tiles[2 * tI + 1];
  int rows = cnt[e] - m0;
  int base = e * NTOK + m0;

  char (*sA)[16384] = sh->sA;
  char (*sB)[8192] = sh->sB;
  int* tokL = sh->tokL;
  float* wgtL = sh->wgtL;

  int tid = threadIdx.x;
  if (tid < 128) {
    int tok = list[base + tid] & (NTOK - 1);  // pad slots clamp to a valid token
    tokL[tid] = tok;
    if (LAYER == 2) wgtL[tid] = wgt[tok];
  }
  __syncthreads();

  int lane = tid & 63, wid = tid >> 6, wm = wid >> 1, wn = wid & 1;

  // A source: per-lane pre-swizzled; dest = wave-uniform chunk base (+lane*16 HW)
  const char* gA[4];
  {
    unsigned sw = (unsigned)(((lane & 7) * 16) ^ ((lane >> 3) << 4));
#pragma unroll
    for (int j = 0; j < 4; j++) {
      int row = wid * 32 + j * 8 + (lane >> 3);
      gA[j] = (const char*)(Xb + (size_t)tokL[row] * K) + sw;
    }
  }
  // B source: linear per-lane walk through this (e, n-block)'s image tiles
  const char* gB = (const char*)img +
                   (size_t)((e * NB + (n0 >> 6)) * KB) * 8192 + wid * 2048 + lane * 16;

  floatx4 acc[4][2];
#pragma unroll
  for (int i = 0; i < 4; i++)
#pragma unroll
    for (int j = 0; j < 2; j++) acc[i][j] = (floatx4){0.f, 0.f, 0.f, 0.f};

#define GLOAD_AB(it, p)                                                     \
  do {                                                                      \
    _Pragma("unroll") for (int j = 0; j < 4; j++)                           \
        gload16(gA[j] + (size_t)(it) * 128, sA[p] + (wid * 4 + j) * 1024);  \
    _Pragma("unroll") for (int j = 0; j < 2; j++)                           \
        gload16(gB + (size_t)(it) * 8192 + j * 1024,                        \
                sB[p] + wid * 2048 + j * 1024);                             \
  } while (0)

#define MFMA_PHASE(P)                                                                    \
  do {                                                                                   \
    const char* A_ = sA[P];                                                              \
    const char* B_ = sB[P];                                                              \
    _Pragma("unroll") for (int kc = 0; kc < 2; kc++) {                                   \
      short8 af[4], bf[2];                                                               \
      int kb = kc * 64 + ((lane >> 4) << 4);                                             \
      _Pragma("unroll") for (int f = 0; f < 4; f++) {                                    \
        int rr = wm * 64 + f * 16 + (lane & 15);                                         \
        af[f] = *(const short8*)(A_ + rr * 128 + (kb ^ ((rr & 7) << 4)));                \
      }                                                                                  \
      _Pragma("unroll") for (int f = 0; f < 2; f++) {                                    \
        int cc = wn * 32 + f * 16 + (lane & 15);                                         \
        bf[f] = *(const short8*)(B_ + cc * 128 + (kb ^ ((cc & 7) << 4)));                \
      }                                                                                  \
      _Pragma("unroll") for (int fm = 0; fm < 4; fm++)                                   \
      _Pragma("unroll") for (int fn = 0; fn < 2; fn++)                                   \
          acc[fm][fn] =                                                                  \
              __builtin_amdgcn_mfma_f32_16x16x32_bf16(af[fm], bf[fn], acc[fm][fn], 0, 0, 0); \
    }                                                                                    \
  } while (0)

  GLOAD_AB(0, 0);
  for (int it = 0; it < NIT - 1; ++it) {
    int p = it & 1;
    __builtin_amdgcn_sched_barrier(0);
    __builtin_amdgcn_s_barrier();  // all reads of buf p^1 (iter it-1) done
    GLOAD_AB(it + 1, p ^ 1);
    __builtin_amdgcn_sched_barrier(0);
    asm volatile("s_waitcnt vmcnt(6)" ::: "memory");  // iter-it loads landed
    __builtin_amdgcn_s_barrier();
    __builtin_amdgcn_sched_barrier(0);
    MFMA_PHASE(p);
  }
  {
    int p = (NIT - 1) & 1;
    __builtin_amdgcn_sched_barrier(0);
    __builtin_amdgcn_s_barrier();
    asm volatile("s_waitcnt vmcnt(0)" ::: "memory");
    __builtin_amdgcn_s_barrier();
    __builtin_amdgcn_sched_barrier(0);
    MFMA_PHASE(p);
  }
#undef GLOAD_AB
#undef MFMA_PHASE

  // epilogue. C frag mapping: col = lane&15, row = (lane>>4)*4 + r
  float bv[2];
#pragma unroll
  for (int f = 0; f < 2; f++) bv[f] = Bias[(size_t)e * N + n0 + wn * 32 + f * 16 + (lane & 15)];
#pragma unroll
  for (int fm = 0; fm < 4; fm++) {
#pragma unroll
    for (int r = 0; r < 4; r++) {
      int gr = wm * 64 + fm * 16 + ((lane >> 4) << 2) + r;
      if (gr < rows) {
        int tok = tokL[gr];
#pragma unroll
        for (int fn = 0; fn < 2; fn++) {
          int col = n0 + wn * 32 + fn * 16 + (lane & 15);
          float v = acc[fm][fn][r] + bv[fn];
          if (LAYER == 1) {
            v = 0.5f * v * (1.0f + erff(v * 0.70710678118654752f));  // exact GELU
            outB[(size_t)tok * FDIM + col] = (unsigned short)bfr(v);
          } else {
            outF[(size_t)tok * DDIM + col] = v * wgtL[gr];
          }
        }
      }
    }
  }
}

// ---- fused B: gemm1 (1440 blocks, flat id keeps x32 -> same-XCD) || prep(w2) ----
__global__ __launch_bounds__(256, 3) void k_fuseB(
    const unsigned short* __restrict__ h16, const unsigned short* __restrict__ img1,
    const float* __restrict__ b1, unsigned short* __restrict__ hid,
    const int* __restrict__ wsI, const int* __restrict__ list,
    const float* __restrict__ w2, unsigned short* __restrict__ img2) {
  __shared__ FuseSh sh;
  int bid = blockIdx.x;
  if (bid < (FDIM / 64) * 45) {
    gemm_body<1>(&sh.g, bid >> 5, (bid & 31) << 6, h16, img1, b1, nullptr, hid,
                 nullptr, wsI, list);
  } else {
    prep_body(sh.t32, w2, img2, FDIM, DDIM, bid - (FDIM / 64) * 45);
  }
}

// ---- gemm2 body: tile 128x128, BK=64, 4 waves (2x2, each 64x64) ----
// Same protocol as gemm_body (double-buffer, 2 raw barriers, counted vmcnt(8)).
// B: two 64-col images per K-step; wave wid loads image (wid>>1), half (wid&1).
__device__ __forceinline__ void gemm2_body128(
    GemmSh2* sh, int tI, int n0,
    const unsigned short* __restrict__ Xb, const unsigned short* __restrict__ img,
    const float* __restrict__ Bias, const float* __restrict__ wgt,
    float* __restrict__ outF, const int* __restrict__ wsI,
    const int* __restrict__ list) {
  constexpr int K = FDIM;   // 2048
  constexpr int N = DDIM;   // 1024
  constexpr int NIT = K / 64;
  constexpr int KB = K / 64, NB = N / 64;

  const int* cnt = wsI;
  const int* ntl = wsI + 48;
  const int* tiles = wsI + 64;

  if (tI >= *ntl) return;
  int e = tiles[2 * tI], m0 = tiles[2 * tI + 1];
  int rows = cnt[e] - m0;
  int base = e * NTOK + m0;

  int tid = threadIdx.x;
  if (tid < 128) {
    int tok = list[base + tid] & (NTOK - 1);
    sh->tokL[tid] = tok;
    sh->wgtL[tid] = wgt[tok];
  }
  __syncthreads();

  int lane = tid & 63, wid = tid >> 6, wm = wid >> 1, wn = wid & 1;

  const char* gA[4];
  {
    unsigned sw = (unsigned)(((lane & 7) * 16) ^ ((lane >> 3) << 4));
#pragma unroll
    for (int j = 0; j < 4; j++) {
      int row = wid * 32 + j * 8 + (lane >> 3);
      gA[j] = (const char*)(Xb + (size_t)sh->tokL[row] * K) + sw;
    }
  }
  // image (n0>>6)+(wid>>1), half (wid&1); dest [0,8K)=image0, [8K,16K)=image1
  const char* gB = (const char*)img +
                   (size_t)((e * NB + (n0 >> 6) + (wid >> 1)) * KB) * 8192 +
                   (wid & 1) * 4096 + lane * 16;

  floatx4 acc[4][4];
#pragma unroll
  for (int i = 0; i < 4; i++)
#pragma unroll
    for (int j = 0; j < 4; j++) acc[i][j] = (floatx4){0.f, 0.f, 0.f, 0.f};

#define GLOAD_AB2(it, p)                                                        \
  do {                                                                          \
    _Pragma("unroll") for (int j = 0; j < 4; j++)                               \
        gload16(gA[j] + (size_t)(it) * 128, sh->sA[p] + (wid * 4 + j) * 1024);  \
    _Pragma("unroll") for (int j = 0; j < 4; j++)                               \
        gload16(gB + (size_t)(it) * 8192 + j * 1024,                            \
                sh->sB[p] + wid * 4096 + j * 1024);                             \
  } while (0)

#define MFMA_PHASE2(P)                                                                   \
  do {                                                                                   \
    const char* A_ = sh->sA[P];                                                          \
    const char* B_ = sh->sB[P];                                                          \
    _Pragma("unroll") for (int kc = 0; kc < 2; kc++) {                                   \
      short8 af[4], bf[4];                                                               \
      int kb = kc * 64 + ((lane >> 4) << 4);                                             \
      _Pragma("unroll") for (int f = 0; f < 4; f++) {                                    \
        int rr = wm * 64 + f * 16 + (lane & 15);                                         \
        af[f] = *(const short8*)(A_ + rr * 128 + (kb ^ ((rr & 7) << 4)));                \
      }                                                                                  \
      _Pragma("unroll") for (int f = 0; f < 4; f++) {                                    \
        int cc = f * 16 + (lane & 15);                                                   \
        bf[f] = *(const short8*)(B_ + wn * 8192 + cc * 128 + (kb ^ ((cc & 7) << 4)));    \
      }                                                                                  \
      _Pragma("unroll") for (int fm = 0; fm < 4; fm++)                                   \
      _Pragma("unroll") for (int fn = 0; fn < 4; fn++)                                   \
          acc[fm][fn] =                                                                  \
              __builtin_amdgcn_mfma_f32_16x16x32_bf16(af[fm], bf[fn], acc[fm][fn], 0, 0, 0); \
    }                                                                                    \
  } while (0)

  GLOAD_AB2(0, 0);
  for (int it = 0; it < NIT - 1; ++it) {
    int p = it & 1;
    __builtin_amdgcn_sched_barrier(0);
    __builtin_amdgcn_s_barrier();
    GLOAD_AB2(it + 1, p ^ 1);
    __builtin_amdgcn_sched_barrier(0);
    asm volatile("s_waitcnt vmcnt(8)" ::: "memory");  // iter-it's 8 loads landed
    __builtin_amdgcn_s_barrier();
    __builtin_amdgcn_sched_barrier(0);
    MFMA_PHASE2(p);
  }
  {
    int p = (NIT - 1) & 1;
    __builtin_amdgcn_sched_barrier(0);
    __builtin_amdgcn_s_barrier();
    asm volatile("s_waitcnt vmcnt(0)" ::: "memory");
    __builtin_amdgcn_s_barrier();
    __builtin_amdgcn_sched_barrier(0);
    MFMA_PHASE2(p);
  }
#undef GLOAD_AB2
#undef MFMA_PHASE2

  float bv[4];
#pragma unroll
  for (int f = 0; f < 4; f++)
    bv[f] = Bias[(size_t)e * N + n0 + wn * 64 + f * 16 + (lane & 15)];
#pragma unroll
  for (int fm = 0; fm < 4; fm++) {
#pragma unroll
    for (int r = 0; r < 4; r++) {
      int gr = wm * 64 + fm * 16 + ((lane >> 4) << 2) + r;
      if (gr < rows) {
        int tok = sh->tokL[gr];
        float w = sh->wgtL[gr];
#pragma unroll
        for (int fn = 0; fn < 4; fn++) {
          int col = n0 + wn * 64 + fn * 16 + (lane & 15);
          outF[(size_t)tok * DDIM + col] = (acc[fm][fn][r] + bv[fn]) * w;
        }
      }
    }
  }
}

__global__ __launch_bounds__(256, 2) void k_gemm2(
    const unsigned short* __restrict__ hid, const unsigned short* __restrict__ img2,
    const float* __restrict__ b2, const float* __restrict__ wgt,
    float* __restrict__ outF, const int* __restrict__ wsI,
    const int* __restrict__ list) {
  __shared__ GemmSh2 sh;
  gemm2_body128(&sh, blockIdx.y, blockIdx.x << 7, hid, img2, b2, wgt, outF,
                wsI, list);
}

extern "C" void kernel_launch(void* const* d_in, const int* in_sizes, int n_in,
                              void* d_out, int out_size, void* d_ws, size_t ws_size,
                              hipStream_t stream) {
  const float* h  = (const float*)d_in[0];
  const float* rw = (const float*)d_in[1];
  const float* w1 = (const float*)d_in[2];
  const float* b1 = (const float*)d_in[3];
  const float* w2 = (const float*)d_in[4];
  const float* b2 = (const float*)d_in[5];
  float* out = (float*)d_out;

  int* wsI = (int*)d_ws;
  int* assign = wsI + 160;
  float* wgt = (float*)(wsI + 4256);
  int* list = (int*)((char*)d_ws + 65536);                           // 14 x 4096 ints
  float* rwT = (float*)((char*)d_ws + 294912);                       // 57KB
  unsigned short* hid  = (unsigned short*)((char*)d_ws + 393216);    // 16.78MB
  unsigned short* h16  = (unsigned short*)((char*)d_ws + 17170432);  // 8.39MB
  unsigned short* img1 = (unsigned short*)((char*)d_ws + 25559040);  // 29.36MB
  unsigned short* img2 = (unsigned short*)((char*)d_ws + 54919168);  // 29.36MB

  k_init<<<56, 256, 0, stream>>>(rw, rwT);
  // router (1024) || prep(w1) (14*32*4 = 1792)
  k_fuseA<<<NTOK / 4 + 1792, 256, 0, stream>>>(h, rwT, assign, wgt, h16, w1, img1);
  k_sort<<<1, 1024, 0, stream>>>(assign, wsI, list, wsI + 64, wsI + 48);
  // gemm1 (32*45 = 1440) || prep(w2) (14*16*8 = 1792)
  k_fuseB<<<1440 + 1792, 256, 0, stream>>>(h16, img1, b1, hid, wsI, list, w2, img2);
  // gemm2: 128x128 tile
  k_gemm2<<<dim3(DDIM / 128, 45), 256, 0, stream>>>(hid, img2, b2, wgt, out, wsI, list);
}